// Round 2
// baseline (1999.235 us; speedup 1.0000x reference)
//
#include <hip/hip_runtime.h>
#include <hip/hip_bf16.h>
#include <math.h>

// ---------------- problem constants ----------------
#define NNODES  10000
#define NEDGES  80000
#define NTOT    90000          // edges + self loops
#define IN_DIM  512
#define H1_DIM  4096
#define H2_DIM  1024
#define ODIM    7
#define MAXDEG  128
#define NEG_SLOPE 0.2f

typedef __hip_bfloat16 bf16;

__device__ inline float ldf(const float* p, size_t i) { return p[i]; }
__device__ inline float ldf(const bf16* p, size_t i)  { return __bfloat162float(p[i]); }
__device__ inline void  stf(float* p, size_t i, float v) { p[i] = v; }
__device__ inline void  stf(bf16* p, size_t i, float v)  { p[i] = __float2bfloat16(v); }

// ---------------- bucket build (CSR-by-dst without sort) ----------------
__global__ void zero_cnt(int* cnt) {
    int i = blockIdx.x * blockDim.x + threadIdx.x;
    if (i < NNODES) cnt[i] = 0;
}

__global__ void build_bucket(const int* __restrict__ ei, int* cnt, int* bucket) {
    int k = blockIdx.x * blockDim.x + threadIdx.x;
    if (k >= NTOT) return;
    int s, d;
    if (k < NEDGES) { s = ei[k]; d = ei[NEDGES + k]; }
    else            { s = k - NEDGES; d = s; }
    int pos = atomicAdd(&cnt[d], 1);
    if (pos < MAXDEG) bucket[d * MAXDEG + pos] = s;
}

// ---------------- fold attention vector through weights: w_out[r] = dot(W[r,:], a) ----------------
__global__ __launch_bounds__(256) void fold_att(const float* __restrict__ W,
                                                const float* __restrict__ a_s,
                                                const float* __restrict__ a_d,
                                                float* __restrict__ w_s,
                                                float* __restrict__ w_d, int C) {
    int r = blockIdx.x;
    const float* row = W + (size_t)r * C;
    float ss = 0.f, sd = 0.f;
    for (int j = threadIdx.x; j < C; j += 256) {
        float w = row[j];
        ss = fmaf(w, a_s[j], ss);
        sd = fmaf(w, a_d[j], sd);
    }
    #pragma unroll
    for (int off = 32; off > 0; off >>= 1) {
        ss += __shfl_down(ss, off);
        sd += __shfl_down(sd, off);
    }
    __shared__ float red[2][4];
    int wave = threadIdx.x >> 6;
    if ((threadIdx.x & 63) == 0) { red[0][wave] = ss; red[1][wave] = sd; }
    __syncthreads();
    if (threadIdx.x == 0) {
        w_s[r] = red[0][0] + red[0][1] + red[0][2] + red[0][3];
        w_d[r] = red[1][0] + red[1][1] + red[1][2] + red[1][3];
    }
}

// ---------------- per-node dots: s_src[n]=dot(H[n,:],w_s), s_dst[n]=dot(H[n,:],w_d) ----------------
template<typename IT>
__global__ __launch_bounds__(256) void node_dots_t(const IT* __restrict__ H,
                                                   const float* __restrict__ w_s,
                                                   const float* __restrict__ w_d,
                                                   float* __restrict__ s_src,
                                                   float* __restrict__ s_dst, int F) {
    int n = blockIdx.x;
    const IT* h = H + (size_t)n * F;
    float ss = 0.f, sd = 0.f;
    for (int f = threadIdx.x; f < F; f += 256) {
        float v = ldf(h, f);
        ss = fmaf(v, w_s[f], ss);
        sd = fmaf(v, w_d[f], sd);
    }
    #pragma unroll
    for (int off = 32; off > 0; off >>= 1) {
        ss += __shfl_down(ss, off);
        sd += __shfl_down(sd, off);
    }
    __shared__ float red[2][4];
    int wave = threadIdx.x >> 6;
    if ((threadIdx.x & 63) == 0) { red[0][wave] = ss; red[1][wave] = sd; }
    __syncthreads();
    if (threadIdx.x == 0) {
        s_src[n] = red[0][0] + red[0][1] + red[0][2] + red[0][3];
        s_dst[n] = red[1][0] + red[1][1] + red[1][2] + red[1][3];
    }
}

// ---------------- segment softmax + weighted gather ----------------
template<typename IT, typename OT, bool BIASRELU>
__global__ __launch_bounds__(256) void aggregate_t(const IT* __restrict__ H,
                                                   const float* __restrict__ s_src,
                                                   const float* __restrict__ s_dst,
                                                   const int* __restrict__ bucket,
                                                   const int* __restrict__ cnt,
                                                   const float* __restrict__ bias,
                                                   OT* __restrict__ OUT, int F) {
    int n = blockIdx.x;
    int c = min(cnt[n], MAXDEG);
    __shared__ float alpha[MAXDEG];
    __shared__ int   ssrc[MAXDEG];
    if (threadIdx.x < c) {
        int s = bucket[n * MAXDEG + threadIdx.x];
        ssrc[threadIdx.x] = s;
        float e = s_src[s] + s_dst[n];
        alpha[threadIdx.x] = (e > 0.f) ? e : NEG_SLOPE * e;
    }
    __syncthreads();
    if (threadIdx.x == 0) {       // true degree ~9 avg, ~30 max: serial is cheap
        float m = -1e30f;
        for (int j = 0; j < c; ++j) m = fmaxf(m, alpha[j]);
        float s = 0.f;
        for (int j = 0; j < c; ++j) { float ex = __expf(alpha[j] - m); alpha[j] = ex; s += ex; }
        float inv = 1.f / s;
        for (int j = 0; j < c; ++j) alpha[j] *= inv;
    }
    __syncthreads();
    for (int f = threadIdx.x; f < F; f += 256) {
        float acc = 0.f;
        for (int j = 0; j < c; ++j)
            acc = fmaf(alpha[j], ldf(H, (size_t)ssrc[j] * F + f), acc);
        if (BIASRELU) acc = fmaxf(acc + bias[f], 0.f);
        stf(OUT, (size_t)n * F + f, acc);
    }
}

// ---------------- fp32-accumulate tiled GEMM: C[M,N] = A[M,K]@B[K,N], bf16 out ----------------
#define BM 64
#define BN 64
#define BK 16

template<typename AT, bool BIASRELU>
__global__ __launch_bounds__(256) void gemm_t(const AT* __restrict__ A,
                                              const float* __restrict__ B,
                                              const float* __restrict__ bias,
                                              bf16* __restrict__ C,
                                              int M, int N, int K) {
    __shared__ float As[BK][BM + 4];
    __shared__ float Bs[BK][BN + 4];
    const int tid = threadIdx.x;
    const int tx  = tid & 15;
    const int ty  = tid >> 4;
    const int row0 = blockIdx.y * BM;
    const int col0 = blockIdx.x * BN;

    float acc[4][4] = {};

    for (int k0 = 0; k0 < K; k0 += BK) {
        #pragma unroll
        for (int i = 0; i < 4; ++i) {
            int idx = tid + i * 256;
            int m = idx >> 4, k = idx & 15;
            int gm = row0 + m;
            As[k][m] = (gm < M) ? ldf(A, (size_t)gm * K + (k0 + k)) : 0.f;
        }
        #pragma unroll
        for (int i = 0; i < 4; ++i) {
            int idx = tid + i * 256;
            int k = idx >> 6, n = idx & 63;
            Bs[k][n] = B[(size_t)(k0 + k) * N + (col0 + n)];
        }
        __syncthreads();
        #pragma unroll
        for (int kk = 0; kk < BK; ++kk) {
            float4 a4 = *(const float4*)&As[kk][ty * 4];
            float4 b4 = *(const float4*)&Bs[kk][tx * 4];
            float av[4] = {a4.x, a4.y, a4.z, a4.w};
            float bv[4] = {b4.x, b4.y, b4.z, b4.w};
            #pragma unroll
            for (int i = 0; i < 4; ++i)
                #pragma unroll
                for (int j = 0; j < 4; ++j)
                    acc[i][j] = fmaf(av[i], bv[j], acc[i][j]);
        }
        __syncthreads();
    }
    #pragma unroll
    for (int i = 0; i < 4; ++i) {
        int gm = row0 + ty * 4 + i;
        if (gm < M) {
            #pragma unroll
            for (int j = 0; j < 4; ++j) {
                int col = col0 + tx * 4 + j;
                float v = acc[i][j];
                if (BIASRELU) v = fmaxf(v + bias[col], 0.f);
                C[(size_t)gm * N + col] = __float2bfloat16(v);
            }
        }
    }
}

// ---------------- layer3: h3 = x3 @ W3 + attention dots on h3 ----------------
__global__ __launch_bounds__(256) void layer3_proj(const bf16* __restrict__ X,
                                                   const float* __restrict__ W,
                                                   const float* __restrict__ a_src,
                                                   const float* __restrict__ a_dst,
                                                   float* __restrict__ H3,
                                                   float* __restrict__ s_src,
                                                   float* __restrict__ s_dst) {
    int n = blockIdx.x;
    const bf16* x = X + (size_t)n * H2_DIM;
    float acc[ODIM] = {};
    for (int k = threadIdx.x; k < H2_DIM; k += 256) {
        float xv = __bfloat162float(x[k]);
        #pragma unroll
        for (int o = 0; o < ODIM; ++o)
            acc[o] = fmaf(xv, W[k * ODIM + o], acc[o]);
    }
    #pragma unroll
    for (int o = 0; o < ODIM; ++o)
        #pragma unroll
        for (int off = 32; off > 0; off >>= 1)
            acc[o] += __shfl_down(acc[o], off);
    __shared__ float red[4][ODIM];
    int wave = threadIdx.x >> 6;
    if ((threadIdx.x & 63) == 0)
        for (int o = 0; o < ODIM; ++o) red[wave][o] = acc[o];
    __syncthreads();
    if (threadIdx.x == 0) {
        float ss = 0.f, sd = 0.f;
        for (int o = 0; o < ODIM; ++o) {
            float v = red[0][o] + red[1][o] + red[2][o] + red[3][o];
            H3[n * ODIM + o] = v;
            ss = fmaf(v, a_src[o], ss);
            sd = fmaf(v, a_dst[o], sd);
        }
        s_src[n] = ss; s_dst[n] = sd;
    }
}

// ---------------- layer3 aggregate + bias + log_softmax ----------------
__global__ __launch_bounds__(128) void aggregate3(const float* __restrict__ H3,
                                                  const float* __restrict__ s_src,
                                                  const float* __restrict__ s_dst,
                                                  const int* __restrict__ bucket,
                                                  const int* __restrict__ cnt,
                                                  const float* __restrict__ b3,
                                                  float* __restrict__ out) {
    int n = blockIdx.x;
    int c = min(cnt[n], MAXDEG);
    __shared__ float alpha[MAXDEG];
    __shared__ int   ssrc[MAXDEG];
    __shared__ float o[ODIM];
    if (threadIdx.x < c) {
        int s = bucket[n * MAXDEG + threadIdx.x];
        ssrc[threadIdx.x] = s;
        float e = s_src[s] + s_dst[n];
        alpha[threadIdx.x] = (e > 0.f) ? e : NEG_SLOPE * e;
    }
    __syncthreads();
    if (threadIdx.x == 0) {
        float m = -1e30f;
        for (int j = 0; j < c; ++j) m = fmaxf(m, alpha[j]);
        float s = 0.f;
        for (int j = 0; j < c; ++j) { float ex = __expf(alpha[j] - m); alpha[j] = ex; s += ex; }
        float inv = 1.f / s;
        for (int j = 0; j < c; ++j) alpha[j] *= inv;
    }
    __syncthreads();
    if (threadIdx.x < ODIM) {
        float acc = 0.f;
        for (int j = 0; j < c; ++j)
            acc = fmaf(alpha[j], H3[ssrc[j] * ODIM + threadIdx.x], acc);
        o[threadIdx.x] = acc + b3[threadIdx.x];
    }
    __syncthreads();
    if (threadIdx.x == 0) {
        float m = o[0];
        for (int k = 1; k < ODIM; ++k) m = fmaxf(m, o[k]);
        float s = 0.f;
        for (int k = 0; k < ODIM; ++k) s += __expf(o[k] - m);
        float lse = m + logf(s);
        for (int k = 0; k < ODIM; ++k) out[n * ODIM + k] = o[k] - lse;
    }
}

// ---------------- host launch ----------------
extern "C" void kernel_launch(void* const* d_in, const int* in_sizes, int n_in,
                              void* d_out, int out_size, void* d_ws, size_t ws_size,
                              hipStream_t stream) {
    const float* x   = (const float*)d_in[0];
    const int*   ei  = (const int*)  d_in[1];
    const float* W1  = (const float*)d_in[2];
    const float* as1 = (const float*)d_in[3];
    const float* ad1 = (const float*)d_in[4];
    const float* b1  = (const float*)d_in[5];
    const float* W2  = (const float*)d_in[6];
    const float* as2 = (const float*)d_in[7];
    const float* ad2 = (const float*)d_in[8];
    const float* b2  = (const float*)d_in[9];
    const float* W3  = (const float*)d_in[10];
    const float* as3 = (const float*)d_in[11];
    const float* ad3 = (const float*)d_in[12];
    const float* b3  = (const float*)d_in[13];
    float* outp = (float*)d_out;

    // workspace layout (~142 MB total)
    char* p = (char*)d_ws;
    bf16*  x2     = (bf16*)p;              p += (size_t)NNODES * H1_DIM * sizeof(bf16);   // 81.92 MB
    bf16*  h2     = (bf16*)p;              p += (size_t)NNODES * H2_DIM * sizeof(bf16);   // 20.48 MB
    bf16*  x3     = (bf16*)p;              p += (size_t)NNODES * H2_DIM * sizeof(bf16);   // 20.48 MB
    float* aggx   = (float*)p;             p += (size_t)NNODES * IN_DIM * sizeof(float);  // 20.48 MB
    float* h3     = (float*)p;             p += (size_t)NNODES * ODIM * sizeof(float);
    float* ssrc   = (float*)p;             p += NNODES * sizeof(float);
    float* sdst   = (float*)p;             p += NNODES * sizeof(float);
    float* w1s    = (float*)p;             p += IN_DIM * sizeof(float);
    float* w1d    = (float*)p;             p += IN_DIM * sizeof(float);
    float* w2s    = (float*)p;             p += H1_DIM * sizeof(float);
    float* w2d    = (float*)p;             p += H1_DIM * sizeof(float);
    int*   cnt    = (int*)p;               p += NNODES * sizeof(int);
    int*   bucket = (int*)p;               p += (size_t)NNODES * MAXDEG * sizeof(int);    // 5.12 MB
    size_t required = (size_t)(p - (char*)d_ws);
    if (ws_size < required) return;   // diagnostic: absmax==ref-magnitude w/o crash => ws too small

    zero_cnt<<<(NNODES + 255) / 256, 256, 0, stream>>>(cnt);
    build_bucket<<<(NTOT + 255) / 256, 256, 0, stream>>>(ei, cnt, bucket);

    // ---- layer 1: fold att, dots on x, aggregate x, then GEMM (+bias+relu) ----
    fold_att<<<IN_DIM, 256, 0, stream>>>(W1, as1, ad1, w1s, w1d, H1_DIM);
    node_dots_t<float><<<NNODES, 256, 0, stream>>>(x, w1s, w1d, ssrc, sdst, IN_DIM);
    aggregate_t<float, float, false><<<NNODES, 256, 0, stream>>>(x, ssrc, sdst, bucket, cnt, nullptr, aggx, IN_DIM);
    {
        dim3 g(H1_DIM / BN, (NNODES + BM - 1) / BM);
        gemm_t<float, true><<<g, 256, 0, stream>>>(aggx, W1, b1, x2, NNODES, H1_DIM, IN_DIM);
    }

    // ---- layer 2: fold att, dots on x2, GEMM, aggregate h2 (+bias+relu) ----
    fold_att<<<H1_DIM, 256, 0, stream>>>(W2, as2, ad2, w2s, w2d, H2_DIM);
    node_dots_t<bf16><<<NNODES, 256, 0, stream>>>(x2, w2s, w2d, ssrc, sdst, H1_DIM);
    {
        dim3 g(H2_DIM / BN, (NNODES + BM - 1) / BM);
        gemm_t<bf16, false><<<g, 256, 0, stream>>>(x2, W2, nullptr, h2, NNODES, H2_DIM, H1_DIM);
    }
    aggregate_t<bf16, bf16, true><<<NNODES, 256, 0, stream>>>(h2, ssrc, sdst, bucket, cnt, b2, x3, H2_DIM);

    // ---- layer 3 ----
    layer3_proj<<<NNODES, 256, 0, stream>>>(x3, W3, as3, ad3, h3, ssrc, sdst);
    aggregate3<<<NNODES, 128, 0, stream>>>(h3, ssrc, sdst, bucket, cnt, b3, outp);
}

// Round 3
// 499.839 us; speedup vs baseline: 3.9998x; 3.9998x over previous
//
#include <hip/hip_runtime.h>
#include <hip/hip_bf16.h>
#include <math.h>

// ---------------- problem constants ----------------
#define NNODES  10000
#define NEDGES  80000
#define NTOT    90000          // edges + self loops
#define IN_DIM  512
#define H1_DIM  4096
#define H2_DIM  1024
#define ODIM    7
#define MAXDEG  128
#define NEG_SLOPE 0.2f

typedef __hip_bfloat16 bf16;
typedef __attribute__((ext_vector_type(8))) short short8;
typedef __attribute__((ext_vector_type(4))) float f32x4;

__device__ inline float ldf(const float* p, size_t i) { return p[i]; }
__device__ inline float ldf(const bf16* p, size_t i)  { return __bfloat162float(p[i]); }
__device__ inline void  stf(float* p, size_t i, float v) { p[i] = v; }
__device__ inline void  stf(bf16* p, size_t i, float v)  { p[i] = __float2bfloat16(v); }

// async global->LDS, 16B per lane; lds ptr must be wave-uniform base (lane*16 added by HW)
#define ASYNC_COPY16(lds, g)                                                              \
    __builtin_amdgcn_global_load_lds((const __attribute__((address_space(1))) void*)(g),  \
                                     (__attribute__((address_space(3))) void*)(lds),      \
                                     16, 0, 0)

// ---------------- bucket build (CSR-by-dst without sort) ----------------
__global__ void zero_cnt(int* cnt) {
    int i = blockIdx.x * blockDim.x + threadIdx.x;
    if (i < NNODES) cnt[i] = 0;
}

__global__ void build_bucket(const int* __restrict__ ei, int* cnt, int* bucket) {
    int k = blockIdx.x * blockDim.x + threadIdx.x;
    if (k >= NTOT) return;
    int s, d;
    if (k < NEDGES) { s = ei[k]; d = ei[NEDGES + k]; }
    else            { s = k - NEDGES; d = s; }
    int pos = atomicAdd(&cnt[d], 1);
    if (pos < MAXDEG) bucket[d * MAXDEG + pos] = s;
}

// ---------------- transpose + fp32->bf16: W[R][C] -> WT[C][R] ----------------
__global__ __launch_bounds__(256) void transpose_bf16(const float* __restrict__ W,
                                                      bf16* __restrict__ WT, int R, int C) {
    __shared__ float t[32][33];
    int c0 = blockIdx.x * 32, r0 = blockIdx.y * 32;
    int x = threadIdx.x & 31, y = threadIdx.x >> 5;   // 32 x 8
    #pragma unroll
    for (int dy = 0; dy < 32; dy += 8)
        t[y + dy][x] = W[(size_t)(r0 + y + dy) * C + c0 + x];
    __syncthreads();
    #pragma unroll
    for (int dy = 0; dy < 32; dy += 8)
        WT[(size_t)(c0 + y + dy) * R + r0 + x] = __float2bfloat16(t[x][y + dy]);
}

// ---------------- fold attention vector through weights: w_out[r] = dot(W[r,:], a) ----------------
__global__ __launch_bounds__(256) void fold_att(const float* __restrict__ W,
                                                const float* __restrict__ a_s,
                                                const float* __restrict__ a_d,
                                                float* __restrict__ w_s,
                                                float* __restrict__ w_d, int C) {
    int r = blockIdx.x;
    const float* row = W + (size_t)r * C;
    float ss = 0.f, sd = 0.f;
    for (int j = threadIdx.x; j < C; j += 256) {
        float w = row[j];
        ss = fmaf(w, a_s[j], ss);
        sd = fmaf(w, a_d[j], sd);
    }
    #pragma unroll
    for (int off = 32; off > 0; off >>= 1) {
        ss += __shfl_down(ss, off);
        sd += __shfl_down(sd, off);
    }
    __shared__ float red[2][4];
    int wave = threadIdx.x >> 6;
    if ((threadIdx.x & 63) == 0) { red[0][wave] = ss; red[1][wave] = sd; }
    __syncthreads();
    if (threadIdx.x == 0) {
        w_s[r] = red[0][0] + red[0][1] + red[0][2] + red[0][3];
        w_d[r] = red[1][0] + red[1][1] + red[1][2] + red[1][3];
    }
}

// ---------------- per-node dots ----------------
template<typename IT>
__global__ __launch_bounds__(256) void node_dots_t(const IT* __restrict__ H,
                                                   const float* __restrict__ w_s,
                                                   const float* __restrict__ w_d,
                                                   float* __restrict__ s_src,
                                                   float* __restrict__ s_dst, int F) {
    int n = blockIdx.x;
    const IT* h = H + (size_t)n * F;
    float ss = 0.f, sd = 0.f;
    for (int f = threadIdx.x; f < F; f += 256) {
        float v = ldf(h, f);
        ss = fmaf(v, w_s[f], ss);
        sd = fmaf(v, w_d[f], sd);
    }
    #pragma unroll
    for (int off = 32; off > 0; off >>= 1) {
        ss += __shfl_down(ss, off);
        sd += __shfl_down(sd, off);
    }
    __shared__ float red[2][4];
    int wave = threadIdx.x >> 6;
    if ((threadIdx.x & 63) == 0) { red[0][wave] = ss; red[1][wave] = sd; }
    __syncthreads();
    if (threadIdx.x == 0) {
        s_src[n] = red[0][0] + red[0][1] + red[0][2] + red[0][3];
        s_dst[n] = red[1][0] + red[1][1] + red[1][2] + red[1][3];
    }
}

// ---------------- segment softmax + weighted gather ----------------
template<typename IT, typename OT, bool BIASRELU>
__global__ __launch_bounds__(256) void aggregate_t(const IT* __restrict__ H,
                                                   const float* __restrict__ s_src,
                                                   const float* __restrict__ s_dst,
                                                   const int* __restrict__ bucket,
                                                   const int* __restrict__ cnt,
                                                   const float* __restrict__ bias,
                                                   OT* __restrict__ OUT, int F) {
    int n = blockIdx.x;
    int c = min(cnt[n], MAXDEG);
    __shared__ float alpha[MAXDEG];
    __shared__ int   ssrc[MAXDEG];
    if (threadIdx.x < c) {
        int s = bucket[n * MAXDEG + threadIdx.x];
        ssrc[threadIdx.x] = s;
        float e = s_src[s] + s_dst[n];
        alpha[threadIdx.x] = (e > 0.f) ? e : NEG_SLOPE * e;
    }
    __syncthreads();
    if (threadIdx.x == 0) {       // true degree ~9 avg, ~30 max
        float m = -1e30f;
        for (int j = 0; j < c; ++j) m = fmaxf(m, alpha[j]);
        float s = 0.f;
        for (int j = 0; j < c; ++j) { float ex = __expf(alpha[j] - m); alpha[j] = ex; s += ex; }
        float inv = 1.f / s;
        for (int j = 0; j < c; ++j) alpha[j] *= inv;
    }
    __syncthreads();
    for (int f = threadIdx.x; f < F; f += 256) {
        float acc = 0.f;
        for (int j = 0; j < c; ++j)
            acc = fmaf(alpha[j], ldf(H, (size_t)ssrc[j] * F + f), acc);
        if (BIASRELU) acc = fmaxf(acc + bias[f], 0.f);
        stf(OUT, (size_t)n * F + f, acc);
    }
}

// ---------------- bf16 MFMA GEMM (gemm_bt): C[M,N] = A[M,K] @ BT[N,K]^T ----------------
// 128x128 block tile, 4 waves, each wave 64x64 via 4x4 mfma_f32_16x16x32_bf16, BK=32,
// global_load_lds width-16 staging (m97 structure). N%128==0, K%32==0; M ragged (clamped).
template<bool BIASRELU>
__global__ __launch_bounds__(256) void gemm_mfma(const bf16* __restrict__ A,
                                                 const bf16* __restrict__ BT,
                                                 const float* __restrict__ bias,
                                                 bf16* __restrict__ C,
                                                 int M, int N, int K) {
    __shared__ alignas(16) bf16 As[128][32];   // 8 KB, row-major, k contiguous
    __shared__ alignas(16) bf16 Bs[128][32];   // 8 KB, BT rows (output cols), k contiguous
    const int tid  = threadIdx.x;
    const int wave = tid >> 6;
    const int lane = tid & 63;
    const int row0 = blockIdx.y * 128;
    const int col0 = blockIdx.x * 128;
    const int wr0  = (wave >> 1) * 64;     // wave quadrant in tile
    const int wc0  = (wave & 1) * 64;

    // staging: thread covers (row = tid>>2, k-chunk = (tid&3)*8), 16B per lane
    const int srow  = tid >> 2;
    const int skoff = (tid & 3) * 8;
    const bf16* ag0 = A  + (size_t)min(row0 + srow,      M - 1) * K + skoff;
    const bf16* ag1 = A  + (size_t)min(row0 + 64 + srow, M - 1) * K + skoff;
    const bf16* bg0 = BT + (size_t)(col0 + srow) * K + skoff;
    const bf16* bg1 = BT + (size_t)(col0 + 64 + srow) * K + skoff;
    bf16* la0 = &As[wave * 16][0];          // wave-uniform LDS bases
    bf16* la1 = &As[64 + wave * 16][0];
    bf16* lb0 = &Bs[wave * 16][0];
    bf16* lb1 = &Bs[64 + wave * 16][0];

    f32x4 acc[4][4] = {};

    const int fRow  = lane & 15;            // fragment row/col within 16
    const int fKoff = (lane >> 4) * 8;      // k offset within 32

    for (int k0 = 0; k0 < K; k0 += 32) {
        ASYNC_COPY16(la0, ag0);
        ASYNC_COPY16(la1, ag1);
        ASYNC_COPY16(lb0, bg0);
        ASYNC_COPY16(lb1, bg1);
        ag0 += 32; ag1 += 32; bg0 += 32; bg1 += 32;
        __syncthreads();                    // drains vmcnt (compiler-inserted) + barrier
        short8 af[4], bfr[4];
        #pragma unroll
        for (int i = 0; i < 4; ++i)
            af[i] = *(const short8*)&As[wr0 + i * 16 + fRow][fKoff];
        #pragma unroll
        for (int j = 0; j < 4; ++j)
            bfr[j] = *(const short8*)&Bs[wc0 + j * 16 + fRow][fKoff];
        #pragma unroll
        for (int i = 0; i < 4; ++i)
            #pragma unroll
            for (int j = 0; j < 4; ++j)
                acc[i][j] = __builtin_amdgcn_mfma_f32_16x16x32_bf16(af[i], bfr[j], acc[i][j], 0, 0, 0);
        __syncthreads();                    // protect LDS for next iteration
    }

    // epilogue: C/D layout col=lane&15, row=(lane>>4)*4+reg [m89/m91]
    const int crow = (lane >> 4) * 4;
    const int ccol = lane & 15;
    #pragma unroll
    for (int i = 0; i < 4; ++i) {
        #pragma unroll
        for (int r = 0; r < 4; ++r) {
            int gm = row0 + wr0 + i * 16 + crow + r;
            if (gm < M) {
                #pragma unroll
                for (int j = 0; j < 4; ++j) {
                    int gn = col0 + wc0 + j * 16 + ccol;
                    float v = acc[i][j][r];
                    if (BIASRELU) v = fmaxf(v + bias[gn], 0.f);
                    C[(size_t)gm * N + gn] = __float2bfloat16(v);
                }
            }
        }
    }
}

// ---------------- layer3: h3 = x3 @ W3 + attention dots on h3 ----------------
__global__ __launch_bounds__(256) void layer3_proj(const bf16* __restrict__ X,
                                                   const float* __restrict__ W,
                                                   const float* __restrict__ a_src,
                                                   const float* __restrict__ a_dst,
                                                   float* __restrict__ H3,
                                                   float* __restrict__ s_src,
                                                   float* __restrict__ s_dst) {
    int n = blockIdx.x;
    const bf16* x = X + (size_t)n * H2_DIM;
    float acc[ODIM] = {};
    for (int k = threadIdx.x; k < H2_DIM; k += 256) {
        float xv = __bfloat162float(x[k]);
        #pragma unroll
        for (int o = 0; o < ODIM; ++o)
            acc[o] = fmaf(xv, W[k * ODIM + o], acc[o]);
    }
    #pragma unroll
    for (int o = 0; o < ODIM; ++o)
        #pragma unroll
        for (int off = 32; off > 0; off >>= 1)
            acc[o] += __shfl_down(acc[o], off);
    __shared__ float red[4][ODIM];
    int wave = threadIdx.x >> 6;
    if ((threadIdx.x & 63) == 0)
        for (int o = 0; o < ODIM; ++o) red[wave][o] = acc[o];
    __syncthreads();
    if (threadIdx.x == 0) {
        float ss = 0.f, sd = 0.f;
        for (int o = 0; o < ODIM; ++o) {
            float v = red[0][o] + red[1][o] + red[2][o] + red[3][o];
            H3[n * ODIM + o] = v;
            ss = fmaf(v, a_src[o], ss);
            sd = fmaf(v, a_dst[o], sd);
        }
        s_src[n] = ss; s_dst[n] = sd;
    }
}

// ---------------- layer3 aggregate + bias + log_softmax ----------------
__global__ __launch_bounds__(128) void aggregate3(const float* __restrict__ H3,
                                                  const float* __restrict__ s_src,
                                                  const float* __restrict__ s_dst,
                                                  const int* __restrict__ bucket,
                                                  const int* __restrict__ cnt,
                                                  const float* __restrict__ b3,
                                                  float* __restrict__ out) {
    int n = blockIdx.x;
    int c = min(cnt[n], MAXDEG);
    __shared__ float alpha[MAXDEG];
    __shared__ int   ssrc[MAXDEG];
    __shared__ float o[ODIM];
    if (threadIdx.x < c) {
        int s = bucket[n * MAXDEG + threadIdx.x];
        ssrc[threadIdx.x] = s;
        float e = s_src[s] + s_dst[n];
        alpha[threadIdx.x] = (e > 0.f) ? e : NEG_SLOPE * e;
    }
    __syncthreads();
    if (threadIdx.x == 0) {
        float m = -1e30f;
        for (int j = 0; j < c; ++j) m = fmaxf(m, alpha[j]);
        float s = 0.f;
        for (int j = 0; j < c; ++j) { float ex = __expf(alpha[j] - m); alpha[j] = ex; s += ex; }
        float inv = 1.f / s;
        for (int j = 0; j < c; ++j) alpha[j] *= inv;
    }
    __syncthreads();
    if (threadIdx.x < ODIM) {
        float acc = 0.f;
        for (int j = 0; j < c; ++j)
            acc = fmaf(alpha[j], H3[ssrc[j] * ODIM + threadIdx.x], acc);
        o[threadIdx.x] = acc + b3[threadIdx.x];
    }
    __syncthreads();
    if (threadIdx.x == 0) {
        float m = o[0];
        for (int k = 1; k < ODIM; ++k) m = fmaxf(m, o[k]);
        float s = 0.f;
        for (int k = 0; k < ODIM; ++k) s += __expf(o[k] - m);
        float lse = m + logf(s);
        for (int k = 0; k < ODIM; ++k) out[n * ODIM + k] = o[k] - lse;
    }
}

// ---------------- host launch ----------------
extern "C" void kernel_launch(void* const* d_in, const int* in_sizes, int n_in,
                              void* d_out, int out_size, void* d_ws, size_t ws_size,
                              hipStream_t stream) {
    const float* x   = (const float*)d_in[0];
    const int*   ei  = (const int*)  d_in[1];
    const float* W1  = (const float*)d_in[2];
    const float* as1 = (const float*)d_in[3];
    const float* ad1 = (const float*)d_in[4];
    const float* b1  = (const float*)d_in[5];
    const float* W2  = (const float*)d_in[6];
    const float* as2 = (const float*)d_in[7];
    const float* ad2 = (const float*)d_in[8];
    const float* b2  = (const float*)d_in[9];
    const float* W3  = (const float*)d_in[10];
    const float* as3 = (const float*)d_in[11];
    const float* ad3 = (const float*)d_in[12];
    const float* b3  = (const float*)d_in[13];
    float* outp = (float*)d_out;

    // workspace layout with aliasing (~137 MB); regions reused across phases:
    //   r2: aggxb (live until GEMM1) -> h2 (written by GEMM2)
    //   r3: W1T   (live until GEMM1) -> x3 (written by layer2 aggregate)
    char* p = (char*)d_ws;
    bf16*  x2     = (bf16*)p;   p += (size_t)NNODES * H1_DIM * sizeof(bf16);   // 81.92 MB
    bf16*  r2     = (bf16*)p;   p += (size_t)NNODES * H2_DIM * sizeof(bf16);   // 20.48 MB
    bf16*  r3     = (bf16*)p;   p += (size_t)NNODES * H2_DIM * sizeof(bf16);   // 20.48 MB
    bf16*  W2T    = (bf16*)p;   p += (size_t)H2_DIM * H1_DIM * sizeof(bf16);   // 8.39 MB
    float* h3     = (float*)p;  p += (size_t)NNODES * ODIM * sizeof(float);
    float* ssrc   = (float*)p;  p += NNODES * sizeof(float);
    float* sdst   = (float*)p;  p += NNODES * sizeof(float);
    float* w1s    = (float*)p;  p += IN_DIM * sizeof(float);
    float* w1d    = (float*)p;  p += IN_DIM * sizeof(float);
    float* w2s    = (float*)p;  p += H1_DIM * sizeof(float);
    float* w2d    = (float*)p;  p += H1_DIM * sizeof(float);
    int*   cnt    = (int*)p;    p += NNODES * sizeof(int);
    int*   bucket = (int*)p;    p += (size_t)NNODES * MAXDEG * sizeof(int);    // 5.12 MB
    size_t required = (size_t)(p - (char*)d_ws);
    if (ws_size < required) return;

    bf16* aggxb = r2;              // [10000][512]  (fits in r2)
    bf16* h2    = r2;              // [10000][1024] (after aggxb dead)
    bf16* W1T   = r3;              // [4096][512]   (fits in r3)
    bf16* x3    = r3;              // [10000][1024] (after W1T dead)

    zero_cnt<<<(NNODES + 255) / 256, 256, 0, stream>>>(cnt);
    build_bucket<<<(NTOT + 255) / 256, 256, 0, stream>>>(ei, cnt, bucket);

    // ---- layer 1: fold att, dots on x, aggregate x (bf16), MFMA GEMM (+bias+relu) ----
    fold_att<<<IN_DIM, 256, 0, stream>>>(W1, as1, ad1, w1s, w1d, H1_DIM);
    node_dots_t<float><<<NNODES, 256, 0, stream>>>(x, w1s, w1d, ssrc, sdst, IN_DIM);
    aggregate_t<float, bf16, false><<<NNODES, 256, 0, stream>>>(x, ssrc, sdst, bucket, cnt, nullptr, aggxb, IN_DIM);
    {
        dim3 tg(H1_DIM / 32, IN_DIM / 32);
        transpose_bf16<<<tg, 256, 0, stream>>>(W1, W1T, IN_DIM, H1_DIM);
        dim3 g(H1_DIM / 128, (NNODES + 127) / 128);
        gemm_mfma<true><<<g, 256, 0, stream>>>(aggxb, W1T, b1, x2, NNODES, H1_DIM, IN_DIM);
    }

    // ---- layer 2: fold att, dots on x2, MFMA GEMM, aggregate h2 (+bias+relu) ----
    fold_att<<<H1_DIM, 256, 0, stream>>>(W2, as2, ad2, w2s, w2d, H2_DIM);
    node_dots_t<bf16><<<NNODES, 256, 0, stream>>>(x2, w2s, w2d, ssrc, sdst, H1_DIM);
    {
        dim3 tg(H2_DIM / 32, H1_DIM / 32);
        transpose_bf16<<<tg, 256, 0, stream>>>(W2, W2T, H1_DIM, H2_DIM);
        dim3 g(H2_DIM / 128, (NNODES + 127) / 128);
        gemm_mfma<false><<<g, 256, 0, stream>>>(x2, W2T, nullptr, h2, NNODES, H2_DIM, H1_DIM);
    }
    aggregate_t<bf16, bf16, true><<<NNODES, 256, 0, stream>>>(h2, ssrc, sdst, bucket, cnt, b2, x3, H2_DIM);

    // ---- layer 3 ----
    layer3_proj<<<NNODES, 256, 0, stream>>>(x3, W3, as3, ad3, h3, ssrc, sdst);
    aggregate3<<<NNODES, 128, 0, stream>>>(h3, ssrc, sdst, bucket, cnt, b3, outp);
}

// Round 4
// 461.231 us; speedup vs baseline: 4.3346x; 1.0837x over previous
//
#include <hip/hip_runtime.h>
#include <hip/hip_bf16.h>
#include <math.h>

// ---------------- problem constants ----------------
#define NNODES  10000
#define NEDGES  80000
#define NTOT    90000          // edges + self loops
#define IN_DIM  512
#define H1_DIM  4096
#define H2_DIM  1024
#define ODIM    7
#define MAXDEG  128
#define NEG_SLOPE 0.2f

typedef __hip_bfloat16 bf16;
typedef __attribute__((ext_vector_type(8))) short short8;
typedef __attribute__((ext_vector_type(4))) float f32x4;

__device__ inline float ldf(const float* p, size_t i) { return p[i]; }
__device__ inline float ldf(const bf16* p, size_t i)  { return __bfloat162float(p[i]); }

__device__ inline void unpack_bf2(unsigned u, float& lo, float& hi) {
    union { unsigned i; float f; } a, b;
    a.i = u << 16; b.i = u & 0xffff0000u;
    lo = a.f; hi = b.f;
}

// async global->LDS, 16B per lane; lds ptr must be wave-uniform base (lane*16 added by HW)
#define ASYNC_COPY16(lds, g)                                                              \
    __builtin_amdgcn_global_load_lds((const __attribute__((address_space(1))) void*)(g),  \
                                     (__attribute__((address_space(3))) void*)(lds),      \
                                     16, 0, 0)

// ---------------- bucket build (CSR-by-dst without sort) ----------------
__global__ void build_bucket(const int* __restrict__ ei, int* cnt, int* bucket) {
    int k = blockIdx.x * blockDim.x + threadIdx.x;
    if (k >= NTOT) return;
    int s, d;
    if (k < NEDGES) { s = ei[k]; d = ei[NEDGES + k]; }
    else            { s = k - NEDGES; d = s; }
    int pos = atomicAdd(&cnt[d], 1);
    if (pos < MAXDEG) bucket[d * MAXDEG + pos] = s;
}

// ---------------- transpose + fp32->bf16: W[R][C] -> WT[C][R] ----------------
__global__ __launch_bounds__(256) void transpose_bf16(const float* __restrict__ W,
                                                      bf16* __restrict__ WT, int R, int C) {
    __shared__ float t[32][33];
    int c0 = blockIdx.x * 32, r0 = blockIdx.y * 32;
    int x = threadIdx.x & 31, y = threadIdx.x >> 5;   // 32 x 8
    #pragma unroll
    for (int dy = 0; dy < 32; dy += 8)
        t[y + dy][x] = W[(size_t)(r0 + y + dy) * C + c0 + x];
    __syncthreads();
    #pragma unroll
    for (int dy = 0; dy < 32; dy += 8)
        WT[(size_t)(c0 + y + dy) * R + r0 + x] = __float2bfloat16(t[x][y + dy]);
}

// ---------------- fold attention vector through weights: w_out[r] = dot(W[r,:], a) ----------------
__global__ __launch_bounds__(256) void fold_att(const float* __restrict__ W,
                                                const float* __restrict__ a_s,
                                                const float* __restrict__ a_d,
                                                float* __restrict__ w_s,
                                                float* __restrict__ w_d, int C) {
    int r = blockIdx.x;
    const float* row = W + (size_t)r * C;
    float ss = 0.f, sd = 0.f;
    for (int j = threadIdx.x; j < C; j += 256) {
        float w = row[j];
        ss = fmaf(w, a_s[j], ss);
        sd = fmaf(w, a_d[j], sd);
    }
    #pragma unroll
    for (int off = 32; off > 0; off >>= 1) {
        ss += __shfl_down(ss, off);
        sd += __shfl_down(sd, off);
    }
    __shared__ float red[2][4];
    int wave = threadIdx.x >> 6;
    if ((threadIdx.x & 63) == 0) { red[0][wave] = ss; red[1][wave] = sd; }
    __syncthreads();
    if (threadIdx.x == 0) {
        w_s[r] = red[0][0] + red[0][1] + red[0][2] + red[0][3];
        w_d[r] = red[1][0] + red[1][1] + red[1][2] + red[1][3];
    }
}

// ---------------- layer-1 node dots on x (fp32, F=512), float4 vectorized ----------------
__global__ __launch_bounds__(128) void node_dots1(const float* __restrict__ X,
                                                  const float* __restrict__ w_s,
                                                  const float* __restrict__ w_d,
                                                  float* __restrict__ s_src,
                                                  float* __restrict__ s_dst) {
    int n = blockIdx.x;
    int t = threadIdx.x;                      // 128 threads x float4 = 512
    float4 xv = ((const float4*)(X + (size_t)n * IN_DIM))[t];
    float4 wsv = ((const float4*)w_s)[t];
    float4 wdv = ((const float4*)w_d)[t];
    float ss = xv.x*wsv.x + xv.y*wsv.y + xv.z*wsv.z + xv.w*wsv.w;
    float sd = xv.x*wdv.x + xv.y*wdv.y + xv.z*wdv.z + xv.w*wdv.w;
    #pragma unroll
    for (int off = 32; off > 0; off >>= 1) {
        ss += __shfl_down(ss, off);
        sd += __shfl_down(sd, off);
    }
    __shared__ float red[2][2];
    int wave = t >> 6;
    if ((t & 63) == 0) { red[0][wave] = ss; red[1][wave] = sd; }
    __syncthreads();
    if (t == 0) {
        s_src[n] = red[0][0] + red[0][1];
        s_dst[n] = red[1][0] + red[1][1];
    }
}

// ---------------- layer-1 aggregate: OUT[n] = sum_j alpha_j * X[src_j] (fp32 in, bf16 out, F=512) ----------------
__global__ __launch_bounds__(128) void agg1(const float* __restrict__ X,
                                            const float* __restrict__ s_src,
                                            const float* __restrict__ s_dst,
                                            const int* __restrict__ bucket,
                                            const int* __restrict__ cnt,
                                            bf16* __restrict__ OUT) {
    int n = blockIdx.x;
    int c = min(cnt[n], MAXDEG);
    __shared__ float alpha[MAXDEG];
    __shared__ int   ssrc[MAXDEG];
    if (threadIdx.x < c) {
        int s = bucket[n * MAXDEG + threadIdx.x];
        ssrc[threadIdx.x] = s;
        float e = s_src[s] + s_dst[n];
        alpha[threadIdx.x] = (e > 0.f) ? e : NEG_SLOPE * e;
    }
    __syncthreads();
    if (threadIdx.x == 0) {
        float m = -1e30f;
        for (int j = 0; j < c; ++j) m = fmaxf(m, alpha[j]);
        float s = 0.f;
        for (int j = 0; j < c; ++j) { float ex = __expf(alpha[j] - m); alpha[j] = ex; s += ex; }
        float inv = 1.f / s;
        for (int j = 0; j < c; ++j) alpha[j] *= inv;
    }
    __syncthreads();
    int t = threadIdx.x;                       // 128 threads x float4 = 512
    float4 acc = {0.f, 0.f, 0.f, 0.f};
    for (int j = 0; j < c; ++j) {
        float a = alpha[j];
        float4 v = ((const float4*)(X + (size_t)ssrc[j] * IN_DIM))[t];
        acc.x = fmaf(a, v.x, acc.x); acc.y = fmaf(a, v.y, acc.y);
        acc.z = fmaf(a, v.z, acc.z); acc.w = fmaf(a, v.w, acc.w);
    }
    bf16 o[4] = { __float2bfloat16(acc.x), __float2bfloat16(acc.y),
                  __float2bfloat16(acc.z), __float2bfloat16(acc.w) };
    *(uint2*)(OUT + (size_t)n * IN_DIM + 4 * t) = *(uint2*)o;
}

// ---------------- layer-2 aggregate: bf16 in/out, F=1024, +bias+relu ----------------
__global__ __launch_bounds__(128) void agg2(const bf16* __restrict__ H,
                                            const float* __restrict__ s_src,
                                            const float* __restrict__ s_dst,
                                            const int* __restrict__ bucket,
                                            const int* __restrict__ cnt,
                                            const float* __restrict__ bias,
                                            bf16* __restrict__ OUT) {
    int n = blockIdx.x;
    int c = min(cnt[n], MAXDEG);
    __shared__ float alpha[MAXDEG];
    __shared__ int   ssrc[MAXDEG];
    if (threadIdx.x < c) {
        int s = bucket[n * MAXDEG + threadIdx.x];
        ssrc[threadIdx.x] = s;
        float e = s_src[s] + s_dst[n];
        alpha[threadIdx.x] = (e > 0.f) ? e : NEG_SLOPE * e;
    }
    __syncthreads();
    if (threadIdx.x == 0) {
        float m = -1e30f;
        for (int j = 0; j < c; ++j) m = fmaxf(m, alpha[j]);
        float s = 0.f;
        for (int j = 0; j < c; ++j) { float ex = __expf(alpha[j] - m); alpha[j] = ex; s += ex; }
        float inv = 1.f / s;
        for (int j = 0; j < c; ++j) alpha[j] *= inv;
    }
    __syncthreads();
    int t = threadIdx.x;                       // 128 threads x 8 bf16 = 1024
    float acc[8] = {};
    for (int j = 0; j < c; ++j) {
        float a = alpha[j];
        uint4 raw = ((const uint4*)(H + (size_t)ssrc[j] * H2_DIM))[t];
        float f0, f1, f2, f3, f4, f5, f6, f7;
        unpack_bf2(raw.x, f0, f1); unpack_bf2(raw.y, f2, f3);
        unpack_bf2(raw.z, f4, f5); unpack_bf2(raw.w, f6, f7);
        acc[0] = fmaf(a, f0, acc[0]); acc[1] = fmaf(a, f1, acc[1]);
        acc[2] = fmaf(a, f2, acc[2]); acc[3] = fmaf(a, f3, acc[3]);
        acc[4] = fmaf(a, f4, acc[4]); acc[5] = fmaf(a, f5, acc[5]);
        acc[6] = fmaf(a, f6, acc[6]); acc[7] = fmaf(a, f7, acc[7]);
    }
    bf16 o[8];
    #pragma unroll
    for (int k = 0; k < 8; ++k)
        o[k] = __float2bfloat16(fmaxf(acc[k] + bias[8 * t + k], 0.f));
    *(uint4*)(OUT + (size_t)n * H2_DIM + 8 * t) = *(uint4*)o;
}

// ---------------- bf16 MFMA GEMM (gemm_bt): C[M,N] = A[M,K] @ BT[N,K]^T ----------------
// TM=128 fixed, TN in {64,128}, BK=64 staged as two 32-k halves (m97 layout per half).
// Optional fused epilogue: bias+relu, and attention dots sum_n v*w_s[n] -> atomicAdd s_src/s_dst.
template<int TN, bool BIASRELU, bool FUSEDOTS>
__global__ __launch_bounds__(256) void gemm_mfma(const bf16* __restrict__ A,
                                                 const bf16* __restrict__ BT,
                                                 const float* __restrict__ bias,
                                                 const float* __restrict__ w_s,
                                                 const float* __restrict__ w_d,
                                                 float* __restrict__ s_src,
                                                 float* __restrict__ s_dst,
                                                 bf16* __restrict__ C,
                                                 int M, int N, int K) {
    constexpr int NJ = TN / 32;                 // j-frags per wave
    __shared__ alignas(16) bf16 As[2][128][32];
    __shared__ alignas(16) bf16 Bs[2][TN][32];
    const int tid  = threadIdx.x;
    const int wave = tid >> 6;
    const int lane = tid & 63;
    const int row0 = blockIdx.y * 128;
    const int col0 = blockIdx.x * TN;
    const int wr0  = (wave >> 1) * 64;
    const int wc0  = (wave & 1) * (TN / 2);

    // staging: thread covers (row = tid>>2, 16B chunk = (tid&3)*8 elems) per 64-row group
    const int srow  = tid >> 2;
    const int skoff = (tid & 3) * 8;
    const bf16* agA0 = A + (size_t)min(row0 + srow,      M - 1) * K + skoff;
    const bf16* agA1 = A + (size_t)min(row0 + 64 + srow, M - 1) * K + skoff;
    const bf16* bg0  = BT + (size_t)(col0 + srow) * K + skoff;
    const bf16* bg1  = BT + (size_t)(col0 + (TN == 128 ? 64 : 0) + srow) * K + skoff;

    f32x4 acc[4][NJ] = {};

    const int fRow  = lane & 15;
    const int fKoff = (lane >> 4) * 8;

    for (int k0 = 0; k0 < K; k0 += 64) {
        #pragma unroll
        for (int h = 0; h < 2; ++h) {
            ASYNC_COPY16(&As[h][wave * 16][0],      agA0 + h * 32);
            ASYNC_COPY16(&As[h][64 + wave * 16][0], agA1 + h * 32);
            ASYNC_COPY16(&Bs[h][wave * 16][0],      bg0 + h * 32);
            if constexpr (TN == 128)
                ASYNC_COPY16(&Bs[h][(TN / 2) + wave * 16][0], bg1 + h * 32);
        }
        agA0 += 64; agA1 += 64; bg0 += 64;
        if constexpr (TN == 128) bg1 += 64;
        __syncthreads();
        #pragma unroll
        for (int h = 0; h < 2; ++h) {
            short8 af[4], bfr[NJ];
            #pragma unroll
            for (int i = 0; i < 4; ++i)
                af[i] = *(const short8*)&As[h][wr0 + i * 16 + fRow][fKoff];
            #pragma unroll
            for (int j = 0; j < NJ; ++j)
                bfr[j] = *(const short8*)&Bs[h][wc0 + j * 16 + fRow][fKoff];
            #pragma unroll
            for (int i = 0; i < 4; ++i)
                #pragma unroll
                for (int j = 0; j < NJ; ++j)
                    acc[i][j] = __builtin_amdgcn_mfma_f32_16x16x32_bf16(af[i], bfr[j], acc[i][j], 0, 0, 0);
        }
        __syncthreads();
    }

    // epilogue: C/D layout col=lane&15, row=(lane>>4)*4+reg [m89/m91]
    const int crow = (lane >> 4) * 4;
    const int ccol = lane & 15;
    #pragma unroll
    for (int i = 0; i < 4; ++i) {
        #pragma unroll
        for (int r = 0; r < 4; ++r) {
            int gm = row0 + wr0 + i * 16 + crow + r;
            float vss = 0.f, vsd = 0.f;
            if (gm < M) {
                #pragma unroll
                for (int j = 0; j < NJ; ++j) {
                    int gn = col0 + wc0 + j * 16 + ccol;
                    float v = acc[i][j][r];
                    if (BIASRELU) v = fmaxf(v + bias[gn], 0.f);
                    C[(size_t)gm * N + gn] = __float2bfloat16(v);
                    if (FUSEDOTS) {
                        vss = fmaf(v, w_s[gn], vss);
                        vsd = fmaf(v, w_d[gn], vsd);
                    }
                }
            }
            if (FUSEDOTS) {
                // 16 lanes of a quad share gm; butterfly-reduce then one atomic
                #pragma unroll
                for (int m2 = 1; m2 < 16; m2 <<= 1) {
                    vss += __shfl_xor(vss, m2, 16);
                    vsd += __shfl_xor(vsd, m2, 16);
                }
                if ((lane & 15) == 0 && gm < M) {
                    atomicAdd(&s_src[gm], vss);
                    atomicAdd(&s_dst[gm], vsd);
                }
            }
        }
    }
}

// ---------------- layer3: h3 = x3 @ W3 + attention dots on h3 (vectorized bf16x8 loads) ----------------
__global__ __launch_bounds__(128) void layer3_proj(const bf16* __restrict__ X,
                                                   const float* __restrict__ W,
                                                   const float* __restrict__ a_src,
                                                   const float* __restrict__ a_dst,
                                                   float* __restrict__ H3,
                                                   float* __restrict__ s_src,
                                                   float* __restrict__ s_dst) {
    int n = blockIdx.x;
    int t = threadIdx.x;                       // 128 threads x 8 elems = 1024
    uint4 raw = ((const uint4*)(X + (size_t)n * H2_DIM))[t];
    float xv[8];
    unpack_bf2(raw.x, xv[0], xv[1]); unpack_bf2(raw.y, xv[2], xv[3]);
    unpack_bf2(raw.z, xv[4], xv[5]); unpack_bf2(raw.w, xv[6], xv[7]);
    float acc[ODIM] = {};
    #pragma unroll
    for (int e = 0; e < 8; ++e) {
        const float* wrow = W + (size_t)(8 * t + e) * ODIM;
        #pragma unroll
        for (int o = 0; o < ODIM; ++o)
            acc[o] = fmaf(xv[e], wrow[o], acc[o]);
    }
    #pragma unroll
    for (int o = 0; o < ODIM; ++o)
        #pragma unroll
        for (int off = 32; off > 0; off >>= 1)
            acc[o] += __shfl_down(acc[o], off);
    __shared__ float red[2][ODIM];
    int wave = t >> 6;
    if ((t & 63) == 0)
        #pragma unroll
        for (int o = 0; o < ODIM; ++o) red[wave][o] = acc[o];
    __syncthreads();
    if (t == 0) {
        float ss = 0.f, sd = 0.f;
        #pragma unroll
        for (int o = 0; o < ODIM; ++o) {
            float v = red[0][o] + red[1][o];
            H3[n * ODIM + o] = v;
            ss = fmaf(v, a_src[o], ss);
            sd = fmaf(v, a_dst[o], sd);
        }
        s_src[n] = ss; s_dst[n] = sd;
    }
}

// ---------------- layer3 aggregate + bias + log_softmax ----------------
__global__ __launch_bounds__(128) void aggregate3(const float* __restrict__ H3,
                                                  const float* __restrict__ s_src,
                                                  const float* __restrict__ s_dst,
                                                  const int* __restrict__ bucket,
                                                  const int* __restrict__ cnt,
                                                  const float* __restrict__ b3,
                                                  float* __restrict__ out) {
    int n = blockIdx.x;
    int c = min(cnt[n], MAXDEG);
    __shared__ float alpha[MAXDEG];
    __shared__ int   ssrc[MAXDEG];
    __shared__ float o[ODIM];
    if (threadIdx.x < c) {
        int s = bucket[n * MAXDEG + threadIdx.x];
        ssrc[threadIdx.x] = s;
        float e = s_src[s] + s_dst[n];
        alpha[threadIdx.x] = (e > 0.f) ? e : NEG_SLOPE * e;
    }
    __syncthreads();
    if (threadIdx.x == 0) {
        float m = -1e30f;
        for (int j = 0; j < c; ++j) m = fmaxf(m, alpha[j]);
        float s = 0.f;
        for (int j = 0; j < c; ++j) { float ex = __expf(alpha[j] - m); alpha[j] = ex; s += ex; }
        float inv = 1.f / s;
        for (int j = 0; j < c; ++j) alpha[j] *= inv;
    }
    __syncthreads();
    if (threadIdx.x < ODIM) {
        float acc = 0.f;
        for (int j = 0; j < c; ++j)
            acc = fmaf(alpha[j], H3[ssrc[j] * ODIM + threadIdx.x], acc);
        o[threadIdx.x] = acc + b3[threadIdx.x];
    }
    __syncthreads();
    if (threadIdx.x == 0) {
        float m = o[0];
        for (int k = 1; k < ODIM; ++k) m = fmaxf(m, o[k]);
        float s = 0.f;
        for (int k = 0; k < ODIM; ++k) s += __expf(o[k] - m);
        float lse = m + logf(s);
        for (int k = 0; k < ODIM; ++k) out[n * ODIM + k] = o[k] - lse;
    }
}

// ---------------- host launch ----------------
extern "C" void kernel_launch(void* const* d_in, const int* in_sizes, int n_in,
                              void* d_out, int out_size, void* d_ws, size_t ws_size,
                              hipStream_t stream) {
    const float* x   = (const float*)d_in[0];
    const int*   ei  = (const int*)  d_in[1];
    const float* W1  = (const float*)d_in[2];
    const float* as1 = (const float*)d_in[3];
    const float* ad1 = (const float*)d_in[4];
    const float* b1  = (const float*)d_in[5];
    const float* W2  = (const float*)d_in[6];
    const float* as2 = (const float*)d_in[7];
    const float* ad2 = (const float*)d_in[8];
    const float* b2  = (const float*)d_in[9];
    const float* W3  = (const float*)d_in[10];
    const float* as3 = (const float*)d_in[11];
    const float* ad3 = (const float*)d_in[12];
    const float* b3  = (const float*)d_in[13];
    float* outp = (float*)d_out;

    // workspace layout with aliasing (~137 MB)
    char* p = (char*)d_ws;
    bf16*  x2     = (bf16*)p;   p += (size_t)NNODES * H1_DIM * sizeof(bf16);   // 81.92 MB
    bf16*  r2     = (bf16*)p;   p += (size_t)NNODES * H2_DIM * sizeof(bf16);   // 20.48 MB
    bf16*  r3     = (bf16*)p;   p += (size_t)NNODES * H2_DIM * sizeof(bf16);   // 20.48 MB
    bf16*  W2T    = (bf16*)p;   p += (size_t)H2_DIM * H1_DIM * sizeof(bf16);   // 8.39 MB
    float* h3     = (float*)p;  p += (size_t)NNODES * ODIM * sizeof(float);
    float* ssrc   = (float*)p;  p += NNODES * sizeof(float);
    float* sdst   = (float*)p;  p += NNODES * sizeof(float);                   // contiguous after ssrc
    float* w1s    = (float*)p;  p += IN_DIM * sizeof(float);
    float* w1d    = (float*)p;  p += IN_DIM * sizeof(float);
    float* w2s    = (float*)p;  p += H1_DIM * sizeof(float);
    float* w2d    = (float*)p;  p += H1_DIM * sizeof(float);
    int*   cnt    = (int*)p;    p += NNODES * sizeof(int);
    int*   bucket = (int*)p;    p += (size_t)NNODES * MAXDEG * sizeof(int);    // 5.12 MB
    size_t required = (size_t)(p - (char*)d_ws);
    if (ws_size < required) return;

    bf16* aggxb = r2;              // [10000][512]  (dead after GEMM1)
    bf16* h2    = r2;              // [10000][1024] (written by GEMM2)
    bf16* W1T   = r3;              // [4096][512]   (dead after GEMM1)
    bf16* x3    = r3;              // [10000][1024] (written by agg2)

    hipMemsetAsync(cnt, 0, NNODES * sizeof(int), stream);
    build_bucket<<<(NTOT + 255) / 256, 256, 0, stream>>>(ei, cnt, bucket);

    // ---- layer 1: fold att, dots on x, aggregate x (bf16) ----
    fold_att<<<IN_DIM, 256, 0, stream>>>(W1, as1, ad1, w1s, w1d, H1_DIM);
    node_dots1<<<NNODES, 128, 0, stream>>>(x, w1s, w1d, ssrc, sdst);
    agg1<<<NNODES, 128, 0, stream>>>(x, ssrc, sdst, bucket, cnt, aggxb);

    // ---- GEMM1 (+bias+relu) with fused layer-2 attention dots ----
    fold_att<<<H1_DIM, 256, 0, stream>>>(W2, as2, ad2, w2s, w2d, H2_DIM);
    hipMemsetAsync(ssrc, 0, 2 * NNODES * sizeof(float), stream);   // ssrc+sdst contiguous
    {
        dim3 tg(H1_DIM / 32, IN_DIM / 32);
        transpose_bf16<<<tg, 256, 0, stream>>>(W1, W1T, IN_DIM, H1_DIM);
        dim3 g(H1_DIM / 128, (NNODES + 127) / 128);
        gemm_mfma<128, true, true><<<g, 256, 0, stream>>>(aggxb, W1T, b1, w2s, w2d,
                                                          ssrc, sdst, x2, NNODES, H1_DIM, IN_DIM);
    }

    // ---- GEMM2 (TN=64 for parallelism), then aggregate h2 (+bias+relu) ----
    {
        dim3 tg(H2_DIM / 32, H1_DIM / 32);
        transpose_bf16<<<tg, 256, 0, stream>>>(W2, W2T, H1_DIM, H2_DIM);
        dim3 g(H2_DIM / 64, (NNODES + 127) / 128);
        gemm_mfma<64, false, false><<<g, 256, 0, stream>>>(x2, W2T, nullptr, nullptr, nullptr,
                                                           nullptr, nullptr, h2, NNODES, H2_DIM, H1_DIM);
    }
    agg2<<<NNODES, 128, 0, stream>>>(h2, ssrc, sdst, bucket, cnt, b2, x3);

    // ---- layer 3 ----
    layer3_proj<<<NNODES, 128, 0, stream>>>(x3, W3, as3, ad3, h3, ssrc, sdst);
    aggregate3<<<NNODES, 128, 0, stream>>>(h3, ssrc, sdst, bucket, cnt, b3, outp);
}

// Round 5
// 460.831 us; speedup vs baseline: 4.3383x; 1.0009x over previous
//
#include <hip/hip_runtime.h>
#include <hip/hip_bf16.h>
#include <math.h>

// ---------------- problem constants ----------------
#define NNODES  10000
#define NEDGES  80000
#define NTOT    90000          // edges + self loops
#define IN_DIM  512
#define H1_DIM  4096
#define H2_DIM  1024
#define ODIM    7
#define MAXDEG  128
#define NEG_SLOPE 0.2f

typedef __hip_bfloat16 bf16;
typedef __attribute__((ext_vector_type(8))) short short8;
typedef __attribute__((ext_vector_type(4))) float f32x4;

__device__ inline void unpack_bf2(unsigned u, float& lo, float& hi) {
    union { unsigned i; float f; } a, b;
    a.i = u << 16; b.i = u & 0xffff0000u;
    lo = a.f; hi = b.f;
}

// async global->LDS, 16B per lane; lds ptr must be wave-uniform base (lane*16 added by HW)
#define ASYNC_COPY16(lds, g)                                                              \
    __builtin_amdgcn_global_load_lds((const __attribute__((address_space(1))) void*)(g),  \
                                     (__attribute__((address_space(3))) void*)(lds),      \
                                     16, 0, 0)

// ---------------- bucket build (CSR-by-dst without sort) ----------------
__global__ void build_bucket(const int* __restrict__ ei, int* cnt, int* bucket) {
    int k = blockIdx.x * blockDim.x + threadIdx.x;
    if (k >= NTOT) return;
    int s, d;
    if (k < NEDGES) { s = ei[k]; d = ei[NEDGES + k]; }
    else            { s = k - NEDGES; d = s; }
    int pos = atomicAdd(&cnt[d], 1);
    if (pos < MAXDEG) bucket[d * MAXDEG + pos] = s;
}

// ---------------- x fp32 -> bf16 copy (for gather) ----------------
__global__ __launch_bounds__(256) void cvt_bf16(const float* __restrict__ X,
                                                bf16* __restrict__ XB, size_t n4) {
    size_t i = (size_t)blockIdx.x * blockDim.x + threadIdx.x;
    if (i >= n4) return;
    float4 v = ((const float4*)X)[i];
    bf16 o[4] = { __float2bfloat16(v.x), __float2bfloat16(v.y),
                  __float2bfloat16(v.z), __float2bfloat16(v.w) };
    *(uint2*)(XB + 4 * i) = *(uint2*)o;
}

// ---------------- transpose + fp32->bf16: W[R][C] -> WT[C][R] ----------------
__global__ __launch_bounds__(256) void transpose_bf16(const float* __restrict__ W,
                                                      bf16* __restrict__ WT, int R, int C) {
    __shared__ float t[32][33];
    int c0 = blockIdx.x * 32, r0 = blockIdx.y * 32;
    int x = threadIdx.x & 31, y = threadIdx.x >> 5;   // 32 x 8
    #pragma unroll
    for (int dy = 0; dy < 32; dy += 8)
        t[y + dy][x] = W[(size_t)(r0 + y + dy) * C + c0 + x];
    __syncthreads();
    #pragma unroll
    for (int dy = 0; dy < 32; dy += 8)
        WT[(size_t)(c0 + y + dy) * R + r0 + x] = __float2bfloat16(t[x][y + dy]);
}

// ---------------- fold attention vector through weights: w_out[r] = dot(W[r,:], a) ----------------
__global__ __launch_bounds__(256) void fold_att(const float* __restrict__ W,
                                                const float* __restrict__ a_s,
                                                const float* __restrict__ a_d,
                                                float* __restrict__ w_s,
                                                float* __restrict__ w_d, int C) {
    int r = blockIdx.x;
    const float* row = W + (size_t)r * C;
    float ss = 0.f, sd = 0.f;
    for (int j = threadIdx.x; j < C; j += 256) {
        float w = row[j];
        ss = fmaf(w, a_s[j], ss);
        sd = fmaf(w, a_d[j], sd);
    }
    #pragma unroll
    for (int off = 32; off > 0; off >>= 1) {
        ss += __shfl_down(ss, off);
        sd += __shfl_down(sd, off);
    }
    __shared__ float red[2][4];
    int wave = threadIdx.x >> 6;
    if ((threadIdx.x & 63) == 0) { red[0][wave] = ss; red[1][wave] = sd; }
    __syncthreads();
    if (threadIdx.x == 0) {
        w_s[r] = red[0][0] + red[0][1] + red[0][2] + red[0][3];
        w_d[r] = red[1][0] + red[1][1] + red[1][2] + red[1][3];
    }
}

// ---------------- fold for W3 (small: C=ODIM): w3[k] = dot(W3[k,:], a) ----------------
__global__ __launch_bounds__(256) void fold_att3(const float* __restrict__ W3,
                                                 const float* __restrict__ a_s,
                                                 const float* __restrict__ a_d,
                                                 float* __restrict__ w_s,
                                                 float* __restrict__ w_d) {
    int k = blockIdx.x * blockDim.x + threadIdx.x;
    if (k >= H2_DIM) return;
    float ss = 0.f, sd = 0.f;
    #pragma unroll
    for (int o = 0; o < ODIM; ++o) {
        float w = W3[k * ODIM + o];
        ss = fmaf(w, a_s[o], ss);
        sd = fmaf(w, a_d[o], sd);
    }
    w_s[k] = ss; w_d[k] = sd;
}

// ---------------- layer-1 node dots on x (fp32, F=512), float4 vectorized ----------------
__global__ __launch_bounds__(128) void node_dots1(const float* __restrict__ X,
                                                  const float* __restrict__ w_s,
                                                  const float* __restrict__ w_d,
                                                  float* __restrict__ s_src,
                                                  float* __restrict__ s_dst) {
    int n = blockIdx.x;
    int t = threadIdx.x;                      // 128 threads x float4 = 512
    float4 xv = ((const float4*)(X + (size_t)n * IN_DIM))[t];
    float4 wsv = ((const float4*)w_s)[t];
    float4 wdv = ((const float4*)w_d)[t];
    float ss = xv.x*wsv.x + xv.y*wsv.y + xv.z*wsv.z + xv.w*wsv.w;
    float sd = xv.x*wdv.x + xv.y*wdv.y + xv.z*wdv.z + xv.w*wdv.w;
    #pragma unroll
    for (int off = 32; off > 0; off >>= 1) {
        ss += __shfl_down(ss, off);
        sd += __shfl_down(sd, off);
    }
    __shared__ float red[2][2];
    int wave = t >> 6;
    if ((t & 63) == 0) { red[0][wave] = ss; red[1][wave] = sd; }
    __syncthreads();
    if (t == 0) {
        s_src[n] = red[0][0] + red[0][1];
        s_dst[n] = red[1][0] + red[1][1];
    }
}

// ---------------- layer-1 aggregate: bf16 gather (F=512) -> bf16 out ----------------
__global__ __launch_bounds__(128) void agg1(const bf16* __restrict__ XB,
                                            const float* __restrict__ s_src,
                                            const float* __restrict__ s_dst,
                                            const int* __restrict__ bucket,
                                            const int* __restrict__ cnt,
                                            bf16* __restrict__ OUT) {
    int n = blockIdx.x;
    int c = min(cnt[n], MAXDEG);
    __shared__ float alpha[MAXDEG];
    __shared__ int   ssrc[MAXDEG];
    if (threadIdx.x < c) {
        int s = bucket[n * MAXDEG + threadIdx.x];
        ssrc[threadIdx.x] = s;
        float e = s_src[s] + s_dst[n];
        alpha[threadIdx.x] = (e > 0.f) ? e : NEG_SLOPE * e;
    }
    __syncthreads();
    if (threadIdx.x == 0) {
        float m = -1e30f;
        for (int j = 0; j < c; ++j) m = fmaxf(m, alpha[j]);
        float s = 0.f;
        for (int j = 0; j < c; ++j) { float ex = __expf(alpha[j] - m); alpha[j] = ex; s += ex; }
        float inv = 1.f / s;
        for (int j = 0; j < c; ++j) alpha[j] *= inv;
    }
    __syncthreads();
    int t = threadIdx.x;                       // 128 threads x 4 bf16 = 512
    float acc[4] = {};
    for (int j = 0; j < c; ++j) {
        float a = alpha[j];
        uint2 raw = ((const uint2*)(XB + (size_t)ssrc[j] * IN_DIM))[t];
        float f0, f1, f2, f3;
        unpack_bf2(raw.x, f0, f1); unpack_bf2(raw.y, f2, f3);
        acc[0] = fmaf(a, f0, acc[0]); acc[1] = fmaf(a, f1, acc[1]);
        acc[2] = fmaf(a, f2, acc[2]); acc[3] = fmaf(a, f3, acc[3]);
    }
    bf16 o[4] = { __float2bfloat16(acc[0]), __float2bfloat16(acc[1]),
                  __float2bfloat16(acc[2]), __float2bfloat16(acc[3]) };
    *(uint2*)(OUT + (size_t)n * IN_DIM + 4 * t) = *(uint2*)o;
}

// ---------------- layer-2 aggregate (+bias+relu) + fused layer-3 dots ----------------
__global__ __launch_bounds__(128) void agg2(const bf16* __restrict__ H,
                                            const float* __restrict__ s_src,
                                            const float* __restrict__ s_dst,
                                            const int* __restrict__ bucket,
                                            const int* __restrict__ cnt,
                                            const float* __restrict__ bias,
                                            const float* __restrict__ w3s,
                                            const float* __restrict__ w3d,
                                            bf16* __restrict__ OUT,
                                            float* __restrict__ s3_src,
                                            float* __restrict__ s3_dst) {
    int n = blockIdx.x;
    int c = min(cnt[n], MAXDEG);
    __shared__ float alpha[MAXDEG];
    __shared__ int   ssrc[MAXDEG];
    if (threadIdx.x < c) {
        int s = bucket[n * MAXDEG + threadIdx.x];
        ssrc[threadIdx.x] = s;
        float e = s_src[s] + s_dst[n];
        alpha[threadIdx.x] = (e > 0.f) ? e : NEG_SLOPE * e;
    }
    __syncthreads();
    if (threadIdx.x == 0) {
        float m = -1e30f;
        for (int j = 0; j < c; ++j) m = fmaxf(m, alpha[j]);
        float s = 0.f;
        for (int j = 0; j < c; ++j) { float ex = __expf(alpha[j] - m); alpha[j] = ex; s += ex; }
        float inv = 1.f / s;
        for (int j = 0; j < c; ++j) alpha[j] *= inv;
    }
    __syncthreads();
    int t = threadIdx.x;                       // 128 threads x 8 bf16 = 1024
    float acc[8] = {};
    for (int j = 0; j < c; ++j) {
        float a = alpha[j];
        uint4 raw = ((const uint4*)(H + (size_t)ssrc[j] * H2_DIM))[t];
        float f0, f1, f2, f3, f4, f5, f6, f7;
        unpack_bf2(raw.x, f0, f1); unpack_bf2(raw.y, f2, f3);
        unpack_bf2(raw.z, f4, f5); unpack_bf2(raw.w, f6, f7);
        acc[0] = fmaf(a, f0, acc[0]); acc[1] = fmaf(a, f1, acc[1]);
        acc[2] = fmaf(a, f2, acc[2]); acc[3] = fmaf(a, f3, acc[3]);
        acc[4] = fmaf(a, f4, acc[4]); acc[5] = fmaf(a, f5, acc[5]);
        acc[6] = fmaf(a, f6, acc[6]); acc[7] = fmaf(a, f7, acc[7]);
    }
    bf16 o[8];
    float ds = 0.f, dd = 0.f;
    #pragma unroll
    for (int k = 0; k < 8; ++k) {
        float v = fmaxf(acc[k] + bias[8 * t + k], 0.f);
        o[k] = __float2bfloat16(v);
        ds = fmaf(v, w3s[8 * t + k], ds);
        dd = fmaf(v, w3d[8 * t + k], dd);
    }
    *(uint4*)(OUT + (size_t)n * H2_DIM + 8 * t) = *(uint4*)o;
    #pragma unroll
    for (int off = 32; off > 0; off >>= 1) {
        ds += __shfl_down(ds, off);
        dd += __shfl_down(dd, off);
    }
    __shared__ float red[2][2];
    int wave = t >> 6;
    if ((t & 63) == 0) { red[0][wave] = ds; red[1][wave] = dd; }
    __syncthreads();
    if (t == 0) {
        s3_src[n] = red[0][0] + red[0][1];
        s3_dst[n] = red[1][0] + red[1][1];
    }
}

// ---------------- bf16 MFMA GEMM (gemm_bt): C[M,N] = A[M,K] @ BT[N,K]^T ----------------
// TM=128, TN in {64,128}, BK=64 as two 32-k halves. XOR-swizzled LDS k-chunks:
// lane fetches global chunk ((tid&3) ^ (srow&3)); frag reads use ((lane>>4) ^ (fRow&3)).
// Spreads 16-lane read groups over 16 banks (was 8) -> residual 2-way aliasing (free, m136).
template<int TN, bool BIASRELU, bool FUSEDOTS>
__global__ __launch_bounds__(256) void gemm_mfma(const bf16* __restrict__ A,
                                                 const bf16* __restrict__ BT,
                                                 const float* __restrict__ bias,
                                                 const float* __restrict__ w_s,
                                                 const float* __restrict__ w_d,
                                                 float* __restrict__ s_src,
                                                 float* __restrict__ s_dst,
                                                 bf16* __restrict__ C,
                                                 int M, int N, int K) {
    constexpr int NJ = TN / 32;                 // j-frags per wave
    __shared__ alignas(16) bf16 As[2][128][32];
    __shared__ alignas(16) bf16 Bs[2][TN][32];
    const int tid  = threadIdx.x;
    const int wave = tid >> 6;
    const int lane = tid & 63;
    const int row0 = blockIdx.y * 128;
    const int col0 = blockIdx.x * TN;
    const int wr0  = (wave >> 1) * 64;
    const int wc0  = (wave & 1) * (TN / 2);

    // staging: row = tid>>2, source 16B chunk = (tid&3) ^ (row&3)  [XOR swizzle]
    const int srow  = tid >> 2;
    const int skoff = ((tid & 3) ^ (srow & 3)) * 8;
    const bf16* agA0 = A + (size_t)min(row0 + srow,      M - 1) * K + skoff;
    const bf16* agA1 = A + (size_t)min(row0 + 64 + srow, M - 1) * K + skoff;
    const bf16* bg0  = BT + (size_t)(col0 + srow) * K + skoff;
    const bf16* bg1  = BT + (size_t)(col0 + (TN == 128 ? 64 : 0) + srow) * K + skoff;

    f32x4 acc[4][NJ] = {};

    const int fRow  = lane & 15;
    const int fKoff = (((lane >> 4) ^ (fRow & 3))) * 8;   // inverse swizzle on read

    for (int k0 = 0; k0 < K; k0 += 64) {
        #pragma unroll
        for (int h = 0; h < 2; ++h) {
            ASYNC_COPY16(&As[h][wave * 16][0],      agA0 + h * 32);
            ASYNC_COPY16(&As[h][64 + wave * 16][0], agA1 + h * 32);
            ASYNC_COPY16(&Bs[h][wave * 16][0],      bg0 + h * 32);
            if constexpr (TN == 128)
                ASYNC_COPY16(&Bs[h][(TN / 2) + wave * 16][0], bg1 + h * 32);
        }
        agA0 += 64; agA1 += 64; bg0 += 64;
        if constexpr (TN == 128) bg1 += 64;
        __syncthreads();
        #pragma unroll
        for (int h = 0; h < 2; ++h) {
            short8 af[4], bfr[NJ];
            #pragma unroll
            for (int i = 0; i < 4; ++i)
                af[i] = *(const short8*)&As[h][wr0 + i * 16 + fRow][fKoff];
            #pragma unroll
            for (int j = 0; j < NJ; ++j)
                bfr[j] = *(const short8*)&Bs[h][wc0 + j * 16 + fRow][fKoff];
            #pragma unroll
            for (int i = 0; i < 4; ++i)
                #pragma unroll
                for (int j = 0; j < NJ; ++j)
                    acc[i][j] = __builtin_amdgcn_mfma_f32_16x16x32_bf16(af[i], bfr[j], acc[i][j], 0, 0, 0);
        }
        __syncthreads();
    }

    // epilogue: C/D layout col=lane&15, row=(lane>>4)*4+reg [m89/m91]
    const int crow = (lane >> 4) * 4;
    const int ccol = lane & 15;
    #pragma unroll
    for (int i = 0; i < 4; ++i) {
        #pragma unroll
        for (int r = 0; r < 4; ++r) {
            int gm = row0 + wr0 + i * 16 + crow + r;
            float vss = 0.f, vsd = 0.f;
            if (gm < M) {
                #pragma unroll
                for (int j = 0; j < NJ; ++j) {
                    int gn = col0 + wc0 + j * 16 + ccol;
                    float v = acc[i][j][r];
                    if (BIASRELU) v = fmaxf(v + bias[gn], 0.f);
                    C[(size_t)gm * N + gn] = __float2bfloat16(v);
                    if (FUSEDOTS) {
                        vss = fmaf(v, w_s[gn], vss);
                        vsd = fmaf(v, w_d[gn], vsd);
                    }
                }
            }
            if (FUSEDOTS) {
                #pragma unroll
                for (int m2 = 1; m2 < 16; m2 <<= 1) {
                    vss += __shfl_xor(vss, m2, 16);
                    vsd += __shfl_xor(vsd, m2, 16);
                }
                if ((lane & 15) == 0 && gm < M) {
                    atomicAdd(&s_src[gm], vss);
                    atomicAdd(&s_dst[gm], vsd);
                }
            }
        }
    }
}

// ---------------- layer3: h3 = x3 @ W3 only (dots now fused into agg2) ----------------
__global__ __launch_bounds__(128) void layer3_proj(const bf16* __restrict__ X,
                                                   const float* __restrict__ W,
                                                   float* __restrict__ H3) {
    int n = blockIdx.x;
    int t = threadIdx.x;                       // 128 threads x 8 elems = 1024
    uint4 raw = ((const uint4*)(X + (size_t)n * H2_DIM))[t];
    float xv[8];
    unpack_bf2(raw.x, xv[0], xv[1]); unpack_bf2(raw.y, xv[2], xv[3]);
    unpack_bf2(raw.z, xv[4], xv[5]); unpack_bf2(raw.w, xv[6], xv[7]);
    float acc[ODIM] = {};
    #pragma unroll
    for (int e = 0; e < 8; ++e) {
        const float* wrow = W + (size_t)(8 * t + e) * ODIM;
        #pragma unroll
        for (int o = 0; o < ODIM; ++o)
            acc[o] = fmaf(xv[e], wrow[o], acc[o]);
    }
    #pragma unroll
    for (int o = 0; o < ODIM; ++o)
        #pragma unroll
        for (int off = 32; off > 0; off >>= 1)
            acc[o] += __shfl_down(acc[o], off);
    __shared__ float red[2][ODIM];
    int wave = t >> 6;
    if ((t & 63) == 0)
        #pragma unroll
        for (int o = 0; o < ODIM; ++o) red[wave][o] = acc[o];
    __syncthreads();
    if (t == 0)
        #pragma unroll
        for (int o = 0; o < ODIM; ++o)
            H3[n * ODIM + o] = red[0][o] + red[1][o];
}

// ---------------- layer3 aggregate + bias + log_softmax ----------------
__global__ __launch_bounds__(128) void aggregate3(const float* __restrict__ H3,
                                                  const float* __restrict__ s_src,
                                                  const float* __restrict__ s_dst,
                                                  const int* __restrict__ bucket,
                                                  const int* __restrict__ cnt,
                                                  const float* __restrict__ b3,
                                                  float* __restrict__ out) {
    int n = blockIdx.x;
    int c = min(cnt[n], MAXDEG);
    __shared__ float alpha[MAXDEG];
    __shared__ int   ssrc[MAXDEG];
    __shared__ float o[ODIM];
    if (threadIdx.x < c) {
        int s = bucket[n * MAXDEG + threadIdx.x];
        ssrc[threadIdx.x] = s;
        float e = s_src[s] + s_dst[n];
        alpha[threadIdx.x] = (e > 0.f) ? e : NEG_SLOPE * e;
    }
    __syncthreads();
    if (threadIdx.x == 0) {
        float m = -1e30f;
        for (int j = 0; j < c; ++j) m = fmaxf(m, alpha[j]);
        float s = 0.f;
        for (int j = 0; j < c; ++j) { float ex = __expf(alpha[j] - m); alpha[j] = ex; s += ex; }
        float inv = 1.f / s;
        for (int j = 0; j < c; ++j) alpha[j] *= inv;
    }
    __syncthreads();
    if (threadIdx.x < ODIM) {
        float acc = 0.f;
        for (int j = 0; j < c; ++j)
            acc = fmaf(alpha[j], H3[ssrc[j] * ODIM + threadIdx.x], acc);
        o[threadIdx.x] = acc + b3[threadIdx.x];
    }
    __syncthreads();
    if (threadIdx.x == 0) {
        float m = o[0];
        for (int k = 1; k < ODIM; ++k) m = fmaxf(m, o[k]);
        float s = 0.f;
        for (int k = 0; k < ODIM; ++k) s += __expf(o[k] - m);
        float lse = m + logf(s);
        for (int k = 0; k < ODIM; ++k) out[n * ODIM + k] = o[k] - lse;
    }
}

// ---------------- host launch ----------------
extern "C" void kernel_launch(void* const* d_in, const int* in_sizes, int n_in,
                              void* d_out, int out_size, void* d_ws, size_t ws_size,
                              hipStream_t stream) {
    const float* x   = (const float*)d_in[0];
    const int*   ei  = (const int*)  d_in[1];
    const float* W1  = (const float*)d_in[2];
    const float* as1 = (const float*)d_in[3];
    const float* ad1 = (const float*)d_in[4];
    const float* b1  = (const float*)d_in[5];
    const float* W2  = (const float*)d_in[6];
    const float* as2 = (const float*)d_in[7];
    const float* ad2 = (const float*)d_in[8];
    const float* b2  = (const float*)d_in[9];
    const float* W3  = (const float*)d_in[10];
    const float* as3 = (const float*)d_in[11];
    const float* ad3 = (const float*)d_in[12];
    const float* b3  = (const float*)d_in[13];
    float* outp = (float*)d_out;

    // workspace layout with aliasing (~137 MB)
    char* p = (char*)d_ws;
    bf16*  x2     = (bf16*)p;   p += (size_t)NNODES * H1_DIM * sizeof(bf16);   // 81.92 MB
    bf16*  r2     = (bf16*)p;   p += (size_t)NNODES * H2_DIM * sizeof(bf16);   // 20.48 MB
    bf16*  r3     = (bf16*)p;   p += (size_t)NNODES * H2_DIM * sizeof(bf16);   // 20.48 MB
    bf16*  W2T    = (bf16*)p;   p += (size_t)H2_DIM * H1_DIM * sizeof(bf16);   // 8.39 MB
    float* h3     = (float*)p;  p += (size_t)NNODES * ODIM * sizeof(float);
    float* ssrc   = (float*)p;  p += NNODES * sizeof(float);
    float* sdst   = (float*)p;  p += NNODES * sizeof(float);                   // contiguous after ssrc
    float* ssrc3  = (float*)p;  p += NNODES * sizeof(float);
    float* sdst3  = (float*)p;  p += NNODES * sizeof(float);
    float* w1s    = (float*)p;  p += IN_DIM * sizeof(float);
    float* w1d    = (float*)p;  p += IN_DIM * sizeof(float);
    float* w2s    = (float*)p;  p += H1_DIM * sizeof(float);
    float* w2d    = (float*)p;  p += H1_DIM * sizeof(float);
    float* w3s    = (float*)p;  p += H2_DIM * sizeof(float);
    float* w3d    = (float*)p;  p += H2_DIM * sizeof(float);
    int*   cnt    = (int*)p;    p += NNODES * sizeof(int);
    int*   bucket = (int*)p;    p += (size_t)NNODES * MAXDEG * sizeof(int);    // 5.12 MB
    size_t required = (size_t)(p - (char*)d_ws);
    if (ws_size < required) return;

    bf16* xb    = x2;              // [10000][512] bf16 copy of x (dead before GEMM1 writes x2)
    bf16* aggxb = r2;              // [10000][512]  (dead after GEMM1)
    bf16* h2    = r2;              // [10000][1024] (written by GEMM2)
    bf16* W1T   = r3;              // [4096][512]   (dead after GEMM1)
    bf16* x3    = r3;              // [10000][1024] (written by agg2)

    hipMemsetAsync(cnt, 0, NNODES * sizeof(int), stream);
    build_bucket<<<(NTOT + 255) / 256, 256, 0, stream>>>(ei, cnt, bucket);

    // ---- layer 1: fold att, dots on x (fp32 exact), bf16 gather aggregate ----
    fold_att<<<IN_DIM, 256, 0, stream>>>(W1, as1, ad1, w1s, w1d, H1_DIM);
    node_dots1<<<NNODES, 128, 0, stream>>>(x, w1s, w1d, ssrc, sdst);
    {
        size_t n4 = (size_t)NNODES * IN_DIM / 4;
        cvt_bf16<<<(unsigned)((n4 + 255) / 256), 256, 0, stream>>>(x, xb, n4);
    }
    agg1<<<NNODES, 128, 0, stream>>>(xb, ssrc, sdst, bucket, cnt, aggxb);

    // ---- GEMM1 (+bias+relu) with fused layer-2 attention dots ----
    fold_att<<<H1_DIM, 256, 0, stream>>>(W2, as2, ad2, w2s, w2d, H2_DIM);
    hipMemsetAsync(ssrc, 0, 2 * NNODES * sizeof(float), stream);   // ssrc+sdst contiguous
    {
        dim3 tg(H1_DIM / 32, IN_DIM / 32);
        transpose_bf16<<<tg, 256, 0, stream>>>(W1, W1T, IN_DIM, H1_DIM);
        dim3 g(H1_DIM / 128, (NNODES + 127) / 128);
        gemm_mfma<128, true, true><<<g, 256, 0, stream>>>(aggxb, W1T, b1, w2s, w2d,
                                                          ssrc, sdst, x2, NNODES, H1_DIM, IN_DIM);
    }

    // ---- GEMM2 (TN=64), then aggregate h2 (+bias+relu) with fused layer-3 dots ----
    fold_att3<<<(H2_DIM + 255) / 256, 256, 0, stream>>>(W3, as3, ad3, w3s, w3d);
    {
        dim3 tg(H2_DIM / 32, H1_DIM / 32);
        transpose_bf16<<<tg, 256, 0, stream>>>(W2, W2T, H1_DIM, H2_DIM);
        dim3 g(H2_DIM / 64, (NNODES + 127) / 128);
        gemm_mfma<64, false, false><<<g, 256, 0, stream>>>(x2, W2T, nullptr, nullptr, nullptr,
                                                           nullptr, nullptr, h2, NNODES, H2_DIM, H1_DIM);
    }
    agg2<<<NNODES, 128, 0, stream>>>(h2, ssrc, sdst, bucket, cnt, b2, w3s, w3d, x3, ssrc3, sdst3);

    // ---- layer 3 ----
    layer3_proj<<<NNODES, 128, 0, stream>>>(x3, W3, h3);
    aggregate3<<<NNODES, 128, 0, stream>>>(h3, ssrc3, sdst3, bucket, cnt, b3, outp);
}